// Round 8
// baseline (1066.958 us; speedup 1.0000x reference)
//
#include <hip/hip_runtime.h>

#define NN 100000
#define NE 1600000
#define KD 128
#define EPSF 1e-5f
#define SCAN_G ((NN + 255) / 256)   // 391 scan blocks
#define RNG 8                       // dst-range partitions (≈1 per XCD)
#define BPR 784                     // blocks per range
#define ECH ((NE + BPR - 1) / BPR)  // edges per block slice (2041)
#define RSZ (NN / RNG)              // 12500 nodes per range
#define WPLANE 16384                // 128*128 weight plane (ushort elems)

typedef __attribute__((ext_vector_type(8))) short bf16x8;
typedef __attribute__((ext_vector_type(8))) unsigned short ushort8;
typedef __attribute__((ext_vector_type(4))) unsigned short ushort4v;
typedef __attribute__((ext_vector_type(4))) float f32x4;

// ---- bf16 split helpers (RNE) ----
__device__ __forceinline__ unsigned short f2bf(float f) {
    unsigned u = __float_as_uint(f);
    u += 0x7FFFu + ((u >> 16) & 1u);
    return (unsigned short)(u >> 16);
}
__device__ __forceinline__ float bfh2f(unsigned short h) {
    return __uint_as_float(((unsigned)h) << 16);
}
__device__ __forceinline__ unsigned packf(float f) {   // (hi<<16)|lo for gather path
    unsigned short h = f2bf(f);
    float lo = f - bfh2f(h);
    unsigned short l = f2bf(lo);
    return ((unsigned)h << 16) | (unsigned)l;
}
__device__ __forceinline__ float unpackf(unsigned p) {
    return __uint_as_float(p & 0xFFFF0000u) + __uint_as_float(p << 16);
}

// ---------------------------------------------------------------- init ----
__global__ void zero_init_kernel(int* __restrict__ cnt, float* __restrict__ bnacc) {
    int i = blockIdx.x * blockDim.x + threadIdx.x;
    if (i < NN) cnt[i] = 0;
    if (i < 512) bnacc[i] = 0.0f;
}

__global__ void hist_ranged_kernel(const int* __restrict__ dst, int* __restrict__ cnt) {
    const int r = blockIdx.x & (RNG - 1);
    const int s = blockIdx.x >> 3;
    const unsigned lo = r * RSZ;
    const int e0 = s * ECH;
    const int e1 = min(e0 + ECH, NE);
    for (int e = e0 + threadIdx.x; e < e1; e += 256) {
        int d = dst[e];
        if ((unsigned)(d - lo) < (unsigned)RSZ) atomicAdd(&cnt[d], 1);
    }
}

__global__ void bsum_kernel(const int* __restrict__ cnt, int* __restrict__ bsum) {
    __shared__ int s[256];
    int i = blockIdx.x * 256 + threadIdx.x;
    s[threadIdx.x] = (i < NN) ? cnt[i] : 0;
    __syncthreads();
#pragma unroll
    for (int off = 128; off > 0; off >>= 1) {
        if (threadIdx.x < off) s[threadIdx.x] += s[threadIdx.x + off];
        __syncthreads();
    }
    if (threadIdx.x == 0) bsum[blockIdx.x] = s[0];
}

__global__ void scan_bsum_kernel(int* __restrict__ bsum) {
    __shared__ int s[512];
    int t = threadIdx.x;
    int v = (t < SCAN_G) ? bsum[t] : 0;
    s[t] = v;
    __syncthreads();
    for (int off = 1; off < 512; off <<= 1) {
        int u = (t >= off) ? s[t - off] : 0;
        __syncthreads();
        s[t] += u;
        __syncthreads();
    }
    if (t < SCAN_G) bsum[t] = s[t] - v;   // exclusive
}

__global__ void scan_local_kernel(int* __restrict__ cnt_cursor, const int* __restrict__ bofs,
                                  int* __restrict__ row_start, float* __restrict__ deg_inv) {
    __shared__ int s[256];
    int i = blockIdx.x * 256 + threadIdx.x;
    int c = (i < NN) ? cnt_cursor[i] : 0;
    s[threadIdx.x] = c;
    __syncthreads();
    for (int off = 1; off < 256; off <<= 1) {
        int v = (threadIdx.x >= off) ? s[threadIdx.x - off] : 0;
        __syncthreads();
        s[threadIdx.x] += v;
        __syncthreads();
    }
    int excl = s[threadIdx.x] - c + bofs[blockIdx.x];
    if (i < NN) {
        row_start[i] = excl;
        cnt_cursor[i] = excl;
        deg_inv[i] = 1.0f / (float)(c > 1 ? c : 1);
    }
    if (i == 0) row_start[NN] = NE;
}

__global__ void scatter_ranged_kernel(const int* __restrict__ src, const int* __restrict__ dst,
                                      int* __restrict__ cursor, int* __restrict__ sorted_src) {
    const int r = blockIdx.x & (RNG - 1);
    const int s = blockIdx.x >> 3;
    const unsigned lo = r * RSZ;
    const int e0 = s * ECH;
    const int e1 = min(e0 + ECH, NE);
    for (int e = e0 + threadIdx.x; e < e1; e += 256) {
        int d = dst[e];
        int sv = src[e];
        if ((unsigned)(d - lo) < (unsigned)RSZ) {
            int p = atomicAdd(&cursor[d], 1);
            sorted_src[p] = sv;
        }
    }
}

// ---------------------------------------------------------- converters ----
__global__ void pack_planes_kernel(const float* __restrict__ X,
                                   unsigned short* __restrict__ Ph,
                                   unsigned short* __restrict__ Pl, int n4) {
    int i = blockIdx.x * 256 + threadIdx.x;
    if (i >= n4) return;
    float4 v = ((const float4*)X)[i];
    ushort4v h, l;
    h.x = f2bf(v.x); l.x = f2bf(v.x - bfh2f(h.x));
    h.y = f2bf(v.y); l.y = f2bf(v.y - bfh2f(h.y));
    h.z = f2bf(v.z); l.z = f2bf(v.z - bfh2f(h.z));
    h.w = f2bf(v.w); l.w = f2bf(v.w - bfh2f(h.w));
    *(ushort4v*)&Ph[i * 4] = h;
    *(ushort4v*)&Pl[i * 4] = l;
}

__global__ void wconv_kernel(const float* w0, const float* w1, const float* w2,
                             const float* w3, const float* w4, const float* w5,
                             const float* w6, const float* w7, const float* w8,
                             const float* w9, const float* w10,
                             unsigned short* __restrict__ P) {
    int i = blockIdx.x * 256 + threadIdx.x;  // float4 index
    if (i >= 43008) return;                  // 10*4096 + 2048
    int seg = i >> 12;
    const float* srcs[11] = {w0, w1, w2, w3, w4, w5, w6, w7, w8, w9, w10};
    const float* s = srcs[seg];
    int off = i - (seg << 12);
    float4 v = ((const float4*)s)[off];
    ushort4v h, l;
    h.x = f2bf(v.x); l.x = f2bf(v.x - bfh2f(h.x));
    h.y = f2bf(v.y); l.y = f2bf(v.y - bfh2f(h.y));
    h.z = f2bf(v.z); l.z = f2bf(v.z - bfh2f(h.z));
    h.w = f2bf(v.w); l.w = f2bf(v.w - bfh2f(h.w));
    *(ushort4v*)&P[(size_t)seg * WPLANE + off * 4] = h;
    *(ushort4v*)&P[(size_t)(11 + seg) * WPLANE + off * 4] = l;
}

// ------------------------------------------------------------ aggregate ----
template <bool PACKED>
__global__ void aggregate_kernel(const float* __restrict__ Xf, const unsigned* __restrict__ Xp,
                                 const int* __restrict__ row_start,
                                 const int* __restrict__ sorted_src,
                                 const float* __restrict__ deg_inv,
                                 unsigned short* __restrict__ Mh,
                                 unsigned short* __restrict__ Ml) {
    int node = blockIdx.x * 8 + (threadIdx.x >> 5);
    int lane = threadIdx.x & 31;
    if (node >= NN) return;
    int e0 = row_start[node];
    int e1 = row_start[node + 1];
    float4 a0 = {0, 0, 0, 0}, a1 = {0, 0, 0, 0}, a2 = {0, 0, 0, 0}, a3 = {0, 0, 0, 0};
    int e = e0;
    for (; e + 4 <= e1; e += 4) {
        int s0 = sorted_src[e + 0];
        int s1 = sorted_src[e + 1];
        int s2 = sorted_src[e + 2];
        int s3 = sorted_src[e + 3];
        if (PACKED) {
            uint4 u0 = *(const uint4*)&Xp[(size_t)s0 * KD + lane * 4];
            uint4 u1 = *(const uint4*)&Xp[(size_t)s1 * KD + lane * 4];
            uint4 u2 = *(const uint4*)&Xp[(size_t)s2 * KD + lane * 4];
            uint4 u3 = *(const uint4*)&Xp[(size_t)s3 * KD + lane * 4];
            a0.x += unpackf(u0.x); a0.y += unpackf(u0.y); a0.z += unpackf(u0.z); a0.w += unpackf(u0.w);
            a1.x += unpackf(u1.x); a1.y += unpackf(u1.y); a1.z += unpackf(u1.z); a1.w += unpackf(u1.w);
            a2.x += unpackf(u2.x); a2.y += unpackf(u2.y); a2.z += unpackf(u2.z); a2.w += unpackf(u2.w);
            a3.x += unpackf(u3.x); a3.y += unpackf(u3.y); a3.z += unpackf(u3.z); a3.w += unpackf(u3.w);
        } else {
            float4 v0 = *(const float4*)&Xf[(size_t)s0 * KD + lane * 4];
            float4 v1 = *(const float4*)&Xf[(size_t)s1 * KD + lane * 4];
            float4 v2 = *(const float4*)&Xf[(size_t)s2 * KD + lane * 4];
            float4 v3 = *(const float4*)&Xf[(size_t)s3 * KD + lane * 4];
            a0.x += v0.x; a0.y += v0.y; a0.z += v0.z; a0.w += v0.w;
            a1.x += v1.x; a1.y += v1.y; a1.z += v1.z; a1.w += v1.w;
            a2.x += v2.x; a2.y += v2.y; a2.z += v2.z; a2.w += v2.w;
            a3.x += v3.x; a3.y += v3.y; a3.z += v3.z; a3.w += v3.w;
        }
    }
    for (; e < e1; e++) {
        int sn = sorted_src[e];
        if (PACKED) {
            uint4 u = *(const uint4*)&Xp[(size_t)sn * KD + lane * 4];
            a0.x += unpackf(u.x); a0.y += unpackf(u.y); a0.z += unpackf(u.z); a0.w += unpackf(u.w);
        } else {
            float4 v = *(const float4*)&Xf[(size_t)sn * KD + lane * 4];
            a0.x += v.x; a0.y += v.y; a0.z += v.z; a0.w += v.w;
        }
    }
    float di = deg_inv[node];
    float4 acc;
    acc.x = ((a0.x + a1.x) + (a2.x + a3.x)) * di;
    acc.y = ((a0.y + a1.y) + (a2.y + a3.y)) * di;
    acc.z = ((a0.z + a1.z) + (a2.z + a3.z)) * di;
    acc.w = ((a0.w + a1.w) + (a2.w + a3.w)) * di;
    ushort4v h, l;
    h.x = f2bf(acc.x); l.x = f2bf(acc.x - bfh2f(h.x));
    h.y = f2bf(acc.y); l.y = f2bf(acc.y - bfh2f(h.y));
    h.z = f2bf(acc.z); l.z = f2bf(acc.z - bfh2f(h.z));
    h.w = f2bf(acc.w); l.w = f2bf(acc.w - bfh2f(h.w));
    *(ushort4v*)&Mh[(size_t)node * KD + lane * 4] = h;
    *(ushort4v*)&Ml[(size_t)node * KD + lane * 4] = l;
}

// ----------------------------------------------------- MFMA split GEMM v3 ----
// C = act( A1@W1^T (+ A2@W2^T) + bias ); pre-split hi/lo bf16 planes.
// R7 lesson: v1/v2 were barrier-bound (2 barriers per 32-K step, ~24 MFMA between).
// v3: B fragments preloaded to REGISTERS straight from global (W is L2-resident;
// each lane's frag is a contiguous 16B chunk) — no W in LDS. A staged to LDS
// ONCE per block at full K=128 (hi+lo, 34 KB, LDK=136 pad -> 2-way max alias).
// Singles: 1 barrier, then 96 MFMAs/wave back-to-back. Duals: 3 barriers total.
template <int NOUT, bool RELU, bool DUAL, bool HILO>
__global__ __launch_bounds__(256, 2) void mgemm3_kernel(
    const unsigned short* __restrict__ A1h, const unsigned short* __restrict__ A1l,
    const unsigned short* __restrict__ A2h, const unsigned short* __restrict__ A2l,
    const unsigned short* __restrict__ W1h, const unsigned short* __restrict__ W1l,
    const unsigned short* __restrict__ W2h, const unsigned short* __restrict__ W2l,
    const float* __restrict__ bias, float* __restrict__ Cf,
    unsigned short* __restrict__ Chi, unsigned short* __restrict__ Clo) {
    constexpr int LDK = 136;                      // 128 + 8 pad (272 B rows, 16B-aligned)
    __shared__ __align__(16) unsigned short Ah_s[64 * LDK];
    __shared__ __align__(16) unsigned short Al_s[64 * LDK];

    const int t = threadIdx.x;
    const int i0 = blockIdx.x * 64;
    const int w = t >> 6, lane = t & 63, quad = lane >> 4, mm = lane & 15;
    constexpr int NT = (NOUT == 128) ? 2 : 1;
    const int colb = w * 16 * NT;

    f32x4 acc[4][NT] = {};
    bf16x8 bh[NT][4], bl[NT][4];

    // ---- preload B fragments (operand 1) from global: 16B/lane, L2-hot ----
#pragma unroll
    for (int nt = 0; nt < NT; nt++) {
        int col = colb + nt * 16 + mm;
#pragma unroll
        for (int ks = 0; ks < 4; ks++) {
            bh[nt][ks] = *(const bf16x8*)&W1h[(size_t)col * KD + ks * 32 + quad * 8];
            bl[nt][ks] = *(const bf16x8*)&W1l[(size_t)col * KD + ks * 32 + quad * 8];
        }
    }

    // ---- stage A (operand 1) full-K to LDS ----
    {
#pragma unroll
        for (int p = 0; p < 4; p++) {
            int c = t + p * 256;                  // ushort8-chunk id, 16 chunks/row
            int row = c >> 4, kc = (c & 15) * 8;
            int gi = min(i0 + row, NN - 1);
            *(ushort8*)&Ah_s[row * LDK + kc] = *(const ushort8*)&A1h[(size_t)gi * KD + kc];
            *(ushort8*)&Al_s[row * LDK + kc] = *(const ushort8*)&A1l[(size_t)gi * KD + kc];
        }
    }
    __syncthreads();

    // ---- compute operand 1: 4 K-steps, no barriers ----
#pragma unroll
    for (int ks = 0; ks < 4; ks++) {
        bf16x8 ah[4], al[4];
#pragma unroll
        for (int mt = 0; mt < 4; mt++) {
            int off = (mt * 16 + mm) * LDK + ks * 32 + quad * 8;
            ah[mt] = *(const bf16x8*)&Ah_s[off];
            al[mt] = *(const bf16x8*)&Al_s[off];
        }
#pragma unroll
        for (int nt = 0; nt < NT; nt++)
#pragma unroll
            for (int mt = 0; mt < 4; mt++) {
                acc[mt][nt] = __builtin_amdgcn_mfma_f32_16x16x32_bf16(ah[mt], bh[nt][ks], acc[mt][nt], 0, 0, 0);
                acc[mt][nt] = __builtin_amdgcn_mfma_f32_16x16x32_bf16(ah[mt], bl[nt][ks], acc[mt][nt], 0, 0, 0);
                acc[mt][nt] = __builtin_amdgcn_mfma_f32_16x16x32_bf16(al[mt], bh[nt][ks], acc[mt][nt], 0, 0, 0);
            }
    }

    if (DUAL) {
        // ---- operand 2: reload B frags, restage A, 3rd barrier pattern ----
#pragma unroll
        for (int nt = 0; nt < NT; nt++) {
            int col = colb + nt * 16 + mm;
#pragma unroll
            for (int ks = 0; ks < 4; ks++) {
                bh[nt][ks] = *(const bf16x8*)&W2h[(size_t)col * KD + ks * 32 + quad * 8];
                bl[nt][ks] = *(const bf16x8*)&W2l[(size_t)col * KD + ks * 32 + quad * 8];
            }
        }
        __syncthreads();                          // all waves done reading A1
#pragma unroll
        for (int p = 0; p < 4; p++) {
            int c = t + p * 256;
            int row = c >> 4, kc = (c & 15) * 8;
            int gi = min(i0 + row, NN - 1);
            *(ushort8*)&Ah_s[row * LDK + kc] = *(const ushort8*)&A2h[(size_t)gi * KD + kc];
            *(ushort8*)&Al_s[row * LDK + kc] = *(const ushort8*)&A2l[(size_t)gi * KD + kc];
        }
        __syncthreads();
#pragma unroll
        for (int ks = 0; ks < 4; ks++) {
            bf16x8 ah[4], al[4];
#pragma unroll
            for (int mt = 0; mt < 4; mt++) {
                int off = (mt * 16 + mm) * LDK + ks * 32 + quad * 8;
                ah[mt] = *(const bf16x8*)&Ah_s[off];
                al[mt] = *(const bf16x8*)&Al_s[off];
            }
#pragma unroll
            for (int nt = 0; nt < NT; nt++)
#pragma unroll
                for (int mt = 0; mt < 4; mt++) {
                    acc[mt][nt] = __builtin_amdgcn_mfma_f32_16x16x32_bf16(ah[mt], bh[nt][ks], acc[mt][nt], 0, 0, 0);
                    acc[mt][nt] = __builtin_amdgcn_mfma_f32_16x16x32_bf16(ah[mt], bl[nt][ks], acc[mt][nt], 0, 0, 0);
                    acc[mt][nt] = __builtin_amdgcn_mfma_f32_16x16x32_bf16(al[mt], bh[nt][ks], acc[mt][nt], 0, 0, 0);
                }
        }
    }

    // ---- epilogue: C/D layout col=lane&15, row=quad*4+reg ----
#pragma unroll
    for (int mt = 0; mt < 4; mt++)
#pragma unroll
        for (int nt = 0; nt < NT; nt++) {
            int col = colb + nt * 16 + mm;
            float bv = bias[col];
#pragma unroll
            for (int r = 0; r < 4; r++) {
                int row = i0 + mt * 16 + quad * 4 + r;
                if (row < NN) {
                    float v = acc[mt][nt][r] + bv;
                    if (RELU) v = fmaxf(v, 0.0f);
                    if (HILO) {
                        unsigned short h = f2bf(v);
                        Chi[(size_t)row * NOUT + col] = h;
                        Clo[(size_t)row * NOUT + col] = f2bf(v - bfh2f(h));
                    } else {
                        Cf[(size_t)row * NOUT + col] = v;
                    }
                }
            }
        }
}

// ------------------------------------------------------------------ BN ----
__global__ void bnstats_kernel(const float* __restrict__ Y, float* __restrict__ acc) {
    int col = threadIdx.x & 127;
    int half = threadIdx.x >> 7;
    float s = 0.0f, q = 0.0f;
    for (int i = blockIdx.x * 2 + half; i < NN; i += gridDim.x * 2) {
        float v = Y[(size_t)i * KD + col];
        s += v;
        q += v * v;
    }
    __shared__ float ls[2][128], lq[2][128];
    ls[half][col] = s;
    lq[half][col] = q;
    __syncthreads();
    if (half == 0) {
        s += ls[1][col];
        q += lq[1][col];
        atomicAdd(&acc[col], s);
        atomicAdd(&acc[128 + col], q);
    }
}

__global__ void bnfinal_kernel(const float* __restrict__ acc, const float* __restrict__ g,
                               const float* __restrict__ b, float* __restrict__ scsh) {
    int c = threadIdx.x;
    float mean = acc[c] * (1.0f / NN);
    float var = acc[128 + c] * (1.0f / NN) - mean * mean;
    float sc = g[c] * rsqrtf(var + EPSF);
    scsh[c] = sc;
    scsh[128 + c] = b[c] - mean * sc;
}

// h = relu(Y*scale+shift)+R  -> packed (for gather) + hi/lo planes (for GEMM)
__global__ void bnrelures_kernel(const float* __restrict__ Y, const float* __restrict__ R,
                                 const float* __restrict__ scsh, unsigned* __restrict__ Op,
                                 unsigned short* __restrict__ Sh, unsigned short* __restrict__ Sl) {
    int idx = blockIdx.x * blockDim.x + threadIdx.x;
    const int total = NN * KD / 4;
    if (idx >= total) return;
    int cg = idx & 31;
    float4 y = ((const float4*)Y)[idx];
    float4 r = ((const float4*)R)[idx];
    float4 sc = ((const float4*)scsh)[cg];
    float4 sh = ((const float4*)scsh)[32 + cg];
    float v0 = fmaxf(y.x * sc.x + sh.x, 0.0f) + r.x;
    float v1 = fmaxf(y.y * sc.y + sh.y, 0.0f) + r.y;
    float v2 = fmaxf(y.z * sc.z + sh.z, 0.0f) + r.z;
    float v3 = fmaxf(y.w * sc.w + sh.w, 0.0f) + r.w;
    ushort4v h, l;
    h.x = f2bf(v0); l.x = f2bf(v0 - bfh2f(h.x));
    h.y = f2bf(v1); l.y = f2bf(v1 - bfh2f(h.y));
    h.z = f2bf(v2); l.z = f2bf(v2 - bfh2f(h.z));
    h.w = f2bf(v3); l.w = f2bf(v3 - bfh2f(h.w));
    uint4 o;
    o.x = ((unsigned)h.x << 16) | l.x;
    o.y = ((unsigned)h.y << 16) | l.y;
    o.z = ((unsigned)h.z << 16) | l.z;
    o.w = ((unsigned)h.w << 16) | l.w;
    ((uint4*)Op)[idx] = o;
    *(ushort4v*)&Sh[idx * 4] = h;
    *(ushort4v*)&Sl[idx * 4] = l;
}

// --------------------------------------------------------------- launch ----
extern "C" void kernel_launch(void* const* d_in, const int* in_sizes, int n_in,
                              void* d_out, int out_size, void* d_ws, size_t ws_size,
                              hipStream_t stream) {
    const float* x      = (const float*)d_in[0];
    const int*   ei     = (const int*)d_in[1];
    const int*   e_src  = ei;
    const int*   e_dst  = ei + NE;
    const float* s1_b   = (const float*)d_in[4];
    const float* s2_b   = (const float*)d_in[7];
    const float* s3_b   = (const float*)d_in[10];
    const float* bn1_g  = (const float*)d_in[11];
    const float* bn1_b  = (const float*)d_in[12];
    const float* bn2_g  = (const float*)d_in[13];
    const float* bn2_b  = (const float*)d_in[14];
    const float* res1_b = (const float*)d_in[16];
    const float* res2_b = (const float*)d_in[18];
    const float* ff1_b  = (const float*)d_in[20];
    const float* ff2_b  = (const float*)d_in[22];
    const float* clf_b  = (const float*)d_in[24];
    float* out = (float*)d_out;

    // workspace carve-up (256B aligned); peak ~290 MB
    char* w = (char*)d_ws;
    auto alloc = [&](size_t bytes) { char* p = w; w += (bytes + 255) & ~(size_t)255; return p; };
    float*          B0   = (float*)alloc((size_t)NN * KD * 4);            // fp32 sage-out
    float*          B1   = (float*)alloc((size_t)NN * KD * 4);            // fp32 residual
    unsigned*       Ppk  = (unsigned*)alloc((size_t)NN * KD * 4);         // packed h (gather)
    unsigned short* S0h  = (unsigned short*)alloc((size_t)NN * KD * 2);   // plane set 0
    unsigned short* S0l  = (unsigned short*)alloc((size_t)NN * KD * 2);
    unsigned short* S1h  = (unsigned short*)alloc((size_t)NN * KD * 2);   // plane set 1
    unsigned short* S1l  = (unsigned short*)alloc((size_t)NN * KD * 2);
    int*   row_start = (int*)alloc((NN + 1) * 4);
    int*   cursor    = (int*)alloc(NN * 4);
    int*   sorted    = (int*)alloc((size_t)NE * 4);
    float* deg_inv   = (float*)alloc(NN * 4);
    float* bnacc     = (float*)alloc(512 * 4);
    float* bnscsh    = (float*)alloc(512 * 4);
    int*   bsum      = (int*)alloc(SCAN_G * 4);
    unsigned short* Wpl = (unsigned short*)alloc((size_t)22 * WPLANE * 2); // 11 hi + 11 lo planes

    auto WH = [&](int j) { return Wpl + (size_t)j * WPLANE; };
    auto WL = [&](int j) { return Wpl + (size_t)(11 + j) * WPLANE; };

    const int GN = (NN + 255) / 256;
    const int GG2 = (NN + 63) / 64;                // 1563 gemm blocks
    const int GA = (NN + 7) / 8;
    const int GV = (NN * KD / 4 + 255) / 256;
    const int GR = RNG * BPR;

    // ---- CSR build (range-partitioned) ----
    zero_init_kernel<<<GN, 256, 0, stream>>>(cursor, bnacc);
    hist_ranged_kernel<<<GR, 256, 0, stream>>>(e_dst, cursor);
    bsum_kernel<<<SCAN_G, 256, 0, stream>>>(cursor, bsum);
    scan_bsum_kernel<<<1, 512, 0, stream>>>(bsum);
    scan_local_kernel<<<SCAN_G, 256, 0, stream>>>(cursor, bsum, row_start, deg_inv);
    scatter_ranged_kernel<<<GR, 256, 0, stream>>>(e_src, e_dst, cursor, sorted);

    // ---- conversions ----
    pack_planes_kernel<<<GV, 256, 0, stream>>>(x, S0h, S0l, NN * KD / 4);   // x -> S0 planes
    wconv_kernel<<<(43008 + 255) / 256, 256, 0, stream>>>(
        (const float*)d_in[15], (const float*)d_in[2], (const float*)d_in[3],   // res1_w, s1_wl, s1_wr
        (const float*)d_in[17], (const float*)d_in[5], (const float*)d_in[6],   // res2_w, s2_wl, s2_wr
        (const float*)d_in[8], (const float*)d_in[9],                            // s3_wl, s3_wr
        (const float*)d_in[19], (const float*)d_in[21], (const float*)d_in[23], // ff1_w, ff2_w, clf_w
        Wpl);

    // ---- block 1 ----
    aggregate_kernel<false><<<GA, 256, 0, stream>>>(x, nullptr, row_start, sorted, deg_inv, S1h, S1l);
    mgemm3_kernel<128, false, false, false><<<GG2, 256, 0, stream>>>(
        S0h, S0l, nullptr, nullptr, WH(0), WL(0), nullptr, nullptr, res1_b, B1, nullptr, nullptr);  // res1
    mgemm3_kernel<128, false, true, false><<<GG2, 256, 0, stream>>>(
        S1h, S1l, S0h, S0l, WH(1), WL(1), WH(2), WL(2), s1_b, B0, nullptr, nullptr);                // sage1
    bnstats_kernel<<<512, 256, 0, stream>>>(B0, bnacc);
    bnfinal_kernel<<<1, 128, 0, stream>>>(bnacc, bn1_g, bn1_b, bnscsh);
    bnrelures_kernel<<<GV, 256, 0, stream>>>(B0, B1, bnscsh, Ppk, S0h, S0l);   // h1 -> Ppk + S0

    // ---- block 2 ----
    aggregate_kernel<true><<<GA, 256, 0, stream>>>(nullptr, Ppk, row_start, sorted, deg_inv, S1h, S1l);
    mgemm3_kernel<128, false, false, false><<<GG2, 256, 0, stream>>>(
        S0h, S0l, nullptr, nullptr, WH(3), WL(3), nullptr, nullptr, res2_b, B1, nullptr, nullptr);  // res2
    mgemm3_kernel<128, false, true, false><<<GG2, 256, 0, stream>>>(
        S1h, S1l, S0h, S0l, WH(4), WL(4), WH(5), WL(5), s2_b, B0, nullptr, nullptr);                // sage2
    bnstats_kernel<<<512, 256, 0, stream>>>(B0, bnacc + 256);
    bnfinal_kernel<<<1, 128, 0, stream>>>(bnacc + 256, bn2_g, bn2_b, bnscsh + 256);
    bnrelures_kernel<<<GV, 256, 0, stream>>>(B0, B1, bnscsh + 256, Ppk, S0h, S0l);  // h2 -> Ppk + S0

    // ---- block 3 + head ----
    aggregate_kernel<true><<<GA, 256, 0, stream>>>(nullptr, Ppk, row_start, sorted, deg_inv, S1h, S1l);
    mgemm3_kernel<128, false, true, true><<<GG2, 256, 0, stream>>>(
        S1h, S1l, S0h, S0l, WH(6), WL(6), WH(7), WL(7), s3_b, nullptr, S0h, S0l);   // sage3 -> S0 (in-place safe: own rows only)
    mgemm3_kernel<128, true, false, true><<<GG2, 256, 0, stream>>>(
        S0h, S0l, nullptr, nullptr, WH(8), WL(8), nullptr, nullptr, ff1_b, nullptr, S1h, S1l);  // ff1+relu
    mgemm3_kernel<128, false, false, true><<<GG2, 256, 0, stream>>>(
        S1h, S1l, nullptr, nullptr, WH(9), WL(9), nullptr, nullptr, ff2_b, nullptr, S0h, S0l);  // ff2
    mgemm3_kernel<64, false, false, false><<<GG2, 256, 0, stream>>>(
        S0h, S0l, nullptr, nullptr, WH(10), WL(10), nullptr, nullptr, clf_b, out, nullptr, nullptr); // clf
}

// Round 9
// 926.835 us; speedup vs baseline: 1.1512x; 1.1512x over previous
//
#include <hip/hip_runtime.h>

#define NN 100000
#define NE 1600000
#define KD 128
#define EPSF 1e-5f
#define SCAN_G ((NN + 255) / 256)   // 391 scan blocks
#define RNG 8                       // dst-range partitions (≈1 per XCD)
#define BPR 784                     // blocks per range
#define ECH ((NE + BPR - 1) / BPR)  // edges per block slice (2041)
#define RSZ (NN / RNG)              // 12500 nodes per range
#define WPLANE 16384                // 128*128 weight plane (ushort elems)
#define LDK 136                     // LDS K-stride (128 + 8 pad)

typedef __attribute__((ext_vector_type(8))) short bf16x8;
typedef __attribute__((ext_vector_type(8))) unsigned short ushort8;
typedef __attribute__((ext_vector_type(4))) unsigned short ushort4v;
typedef __attribute__((ext_vector_type(4))) float f32x4;

// ---- bf16 split helpers (RNE) ----
__device__ __forceinline__ unsigned short f2bf(float f) {
    unsigned u = __float_as_uint(f);
    u += 0x7FFFu + ((u >> 16) & 1u);
    return (unsigned short)(u >> 16);
}
__device__ __forceinline__ float bfh2f(unsigned short h) {
    return __uint_as_float(((unsigned)h) << 16);
}
__device__ __forceinline__ unsigned packf(float f) {   // (hi<<16)|lo
    unsigned short h = f2bf(f);
    float lo = f - bfh2f(h);
    unsigned short l = f2bf(lo);
    return ((unsigned)h << 16) | (unsigned)l;
}
__device__ __forceinline__ float unpackf(unsigned p) {
    return __uint_as_float(p & 0xFFFF0000u) + __uint_as_float(p << 16);
}

// ---------------------------------------------------------------- init ----
__global__ void zero_init_kernel(int* __restrict__ cnt, float* __restrict__ bnacc) {
    int i = blockIdx.x * blockDim.x + threadIdx.x;
    if (i < NN) cnt[i] = 0;
    if (i < 512) bnacc[i] = 0.0f;
}

__global__ void hist_ranged_kernel(const int* __restrict__ dst, int* __restrict__ cnt) {
    const int r = blockIdx.x & (RNG - 1);
    const int s = blockIdx.x >> 3;
    const unsigned lo = r * RSZ;
    const int e0 = s * ECH;
    const int e1 = min(e0 + ECH, NE);
    for (int e = e0 + threadIdx.x; e < e1; e += 256) {
        int d = dst[e];
        if ((unsigned)(d - lo) < (unsigned)RSZ) atomicAdd(&cnt[d], 1);
    }
}

__global__ void bsum_kernel(const int* __restrict__ cnt, int* __restrict__ bsum) {
    __shared__ int s[256];
    int i = blockIdx.x * 256 + threadIdx.x;
    s[threadIdx.x] = (i < NN) ? cnt[i] : 0;
    __syncthreads();
#pragma unroll
    for (int off = 128; off > 0; off >>= 1) {
        if (threadIdx.x < off) s[threadIdx.x] += s[threadIdx.x + off];
        __syncthreads();
    }
    if (threadIdx.x == 0) bsum[blockIdx.x] = s[0];
}

__global__ void scan_bsum_kernel(int* __restrict__ bsum) {
    __shared__ int s[512];
    int t = threadIdx.x;
    int v = (t < SCAN_G) ? bsum[t] : 0;
    s[t] = v;
    __syncthreads();
    for (int off = 1; off < 512; off <<= 1) {
        int u = (t >= off) ? s[t - off] : 0;
        __syncthreads();
        s[t] += u;
        __syncthreads();
    }
    if (t < SCAN_G) bsum[t] = s[t] - v;   // exclusive
}

__global__ void scan_local_kernel(int* __restrict__ cnt_cursor, const int* __restrict__ bofs,
                                  int* __restrict__ row_start, float* __restrict__ deg_inv) {
    __shared__ int s[256];
    int i = blockIdx.x * 256 + threadIdx.x;
    int c = (i < NN) ? cnt_cursor[i] : 0;
    s[threadIdx.x] = c;
    __syncthreads();
    for (int off = 1; off < 256; off <<= 1) {
        int v = (threadIdx.x >= off) ? s[threadIdx.x - off] : 0;
        __syncthreads();
        s[threadIdx.x] += v;
        __syncthreads();
    }
    int excl = s[threadIdx.x] - c + bofs[blockIdx.x];
    if (i < NN) {
        row_start[i] = excl;
        cnt_cursor[i] = excl;
        deg_inv[i] = 1.0f / (float)(c > 1 ? c : 1);
    }
    if (i == 0) row_start[NN] = NE;
}

__global__ void scatter_ranged_kernel(const int* __restrict__ src, const int* __restrict__ dst,
                                      int* __restrict__ cursor, int* __restrict__ sorted_src) {
    const int r = blockIdx.x & (RNG - 1);
    const int s = blockIdx.x >> 3;
    const unsigned lo = r * RSZ;
    const int e0 = s * ECH;
    const int e1 = min(e0 + ECH, NE);
    for (int e = e0 + threadIdx.x; e < e1; e += 256) {
        int d = dst[e];
        int sv = src[e];
        if ((unsigned)(d - lo) < (unsigned)RSZ) {
            int p = atomicAdd(&cursor[d], 1);
            sorted_src[p] = sv;
        }
    }
}

// ---------------------------------------------------------- converters ----
// 11 weight matrices -> hi planes at j*WPLANE, lo planes at (11+j)*WPLANE
__global__ void wconv_kernel(const float* w0, const float* w1, const float* w2,
                             const float* w3, const float* w4, const float* w5,
                             const float* w6, const float* w7, const float* w8,
                             const float* w9, const float* w10,
                             unsigned short* __restrict__ P) {
    int i = blockIdx.x * 256 + threadIdx.x;  // float4 index
    if (i >= 43008) return;                  // 10*4096 + 2048
    int seg = i >> 12;
    const float* srcs[11] = {w0, w1, w2, w3, w4, w5, w6, w7, w8, w9, w10};
    const float* s = srcs[seg];
    int off = i - (seg << 12);
    float4 v = ((const float4*)s)[off];
    ushort4v h, l;
    h.x = f2bf(v.x); l.x = f2bf(v.x - bfh2f(h.x));
    h.y = f2bf(v.y); l.y = f2bf(v.y - bfh2f(h.y));
    h.z = f2bf(v.z); l.z = f2bf(v.z - bfh2f(h.z));
    h.w = f2bf(v.w); l.w = f2bf(v.w - bfh2f(h.w));
    *(ushort4v*)&P[(size_t)seg * WPLANE + off * 4] = h;
    *(ushort4v*)&P[(size_t)(11 + seg) * WPLANE + off * 4] = l;
}

// ------------------------------------------------------------ aggregate ----
// mean over in-neighbors -> fp32. 8 nodes/block, 32 lanes x float4, x4 unroll.
template <bool PACKED>
__global__ void aggregate_kernel(const float* __restrict__ Xf, const unsigned* __restrict__ Xp,
                                 const int* __restrict__ row_start,
                                 const int* __restrict__ sorted_src,
                                 const float* __restrict__ deg_inv, float* __restrict__ Mf) {
    int node = blockIdx.x * 8 + (threadIdx.x >> 5);
    int lane = threadIdx.x & 31;
    if (node >= NN) return;
    int e0 = row_start[node];
    int e1 = row_start[node + 1];
    float4 a0 = {0, 0, 0, 0}, a1 = {0, 0, 0, 0}, a2 = {0, 0, 0, 0}, a3 = {0, 0, 0, 0};
    int e = e0;
    for (; e + 4 <= e1; e += 4) {
        int s0 = sorted_src[e + 0];
        int s1 = sorted_src[e + 1];
        int s2 = sorted_src[e + 2];
        int s3 = sorted_src[e + 3];
        if (PACKED) {
            uint4 u0 = *(const uint4*)&Xp[(size_t)s0 * KD + lane * 4];
            uint4 u1 = *(const uint4*)&Xp[(size_t)s1 * KD + lane * 4];
            uint4 u2 = *(const uint4*)&Xp[(size_t)s2 * KD + lane * 4];
            uint4 u3 = *(const uint4*)&Xp[(size_t)s3 * KD + lane * 4];
            a0.x += unpackf(u0.x); a0.y += unpackf(u0.y); a0.z += unpackf(u0.z); a0.w += unpackf(u0.w);
            a1.x += unpackf(u1.x); a1.y += unpackf(u1.y); a1.z += unpackf(u1.z); a1.w += unpackf(u1.w);
            a2.x += unpackf(u2.x); a2.y += unpackf(u2.y); a2.z += unpackf(u2.z); a2.w += unpackf(u2.w);
            a3.x += unpackf(u3.x); a3.y += unpackf(u3.y); a3.z += unpackf(u3.z); a3.w += unpackf(u3.w);
        } else {
            float4 v0 = *(const float4*)&Xf[(size_t)s0 * KD + lane * 4];
            float4 v1 = *(const float4*)&Xf[(size_t)s1 * KD + lane * 4];
            float4 v2 = *(const float4*)&Xf[(size_t)s2 * KD + lane * 4];
            float4 v3 = *(const float4*)&Xf[(size_t)s3 * KD + lane * 4];
            a0.x += v0.x; a0.y += v0.y; a0.z += v0.z; a0.w += v0.w;
            a1.x += v1.x; a1.y += v1.y; a1.z += v1.z; a1.w += v1.w;
            a2.x += v2.x; a2.y += v2.y; a2.z += v2.z; a2.w += v2.w;
            a3.x += v3.x; a3.y += v3.y; a3.z += v3.z; a3.w += v3.w;
        }
    }
    for (; e < e1; e++) {
        int sn = sorted_src[e];
        if (PACKED) {
            uint4 u = *(const uint4*)&Xp[(size_t)sn * KD + lane * 4];
            a0.x += unpackf(u.x); a0.y += unpackf(u.y); a0.z += unpackf(u.z); a0.w += unpackf(u.w);
        } else {
            float4 v = *(const float4*)&Xf[(size_t)sn * KD + lane * 4];
            a0.x += v.x; a0.y += v.y; a0.z += v.z; a0.w += v.w;
        }
    }
    float di = deg_inv[node];
    float4 acc;
    acc.x = ((a0.x + a1.x) + (a2.x + a3.x)) * di;
    acc.y = ((a0.y + a1.y) + (a2.y + a3.y)) * di;
    acc.z = ((a0.z + a1.z) + (a2.z + a3.z)) * di;
    acc.w = ((a0.w + a1.w) + (a2.w + a3.w)) * di;
    *(float4*)&Mf[(size_t)node * KD + lane * 4] = acc;
}

// ---------------------------------------------------- fused GEMM helpers ----
// Fragment layout (verified R4-R8): A[m=lane&15][k=quad*8+j]; C/D col=lane&15,
// row=quad*4+reg. LDS planes: [row 0..63][k 0..127], stride LDK.

// compute one split product (96 MFMA/wave for NT=2): acc += A_lds @ W^T
template <int NT>
__device__ __forceinline__ void product_from_lds(
    const unsigned short* Ph, const unsigned short* Pl,
    const unsigned short* __restrict__ Wh, const unsigned short* __restrict__ Wl,
    int colb, int quad, int mm, f32x4 (&acc)[4][NT]) {
    bf16x8 wh[NT][4], wl[NT][4];
#pragma unroll
    for (int nt = 0; nt < NT; nt++) {
        int col = colb + nt * 16 + mm;
#pragma unroll
        for (int ks = 0; ks < 4; ks++) {
            wh[nt][ks] = *(const bf16x8*)&Wh[(size_t)col * KD + ks * 32 + quad * 8];
            wl[nt][ks] = *(const bf16x8*)&Wl[(size_t)col * KD + ks * 32 + quad * 8];
        }
    }
#pragma unroll
    for (int ks = 0; ks < 4; ks++) {
        bf16x8 ah[4], al[4];
#pragma unroll
        for (int mt = 0; mt < 4; mt++) {
            int off = (mt * 16 + mm) * LDK + ks * 32 + quad * 8;
            ah[mt] = *(const bf16x8*)&Ph[off];
            al[mt] = *(const bf16x8*)&Pl[off];
        }
#pragma unroll
        for (int nt = 0; nt < NT; nt++)
#pragma unroll
            for (int mt = 0; mt < 4; mt++) {
                acc[mt][nt] = __builtin_amdgcn_mfma_f32_16x16x32_bf16(ah[mt], wh[nt][ks], acc[mt][nt], 0, 0, 0);
                acc[mt][nt] = __builtin_amdgcn_mfma_f32_16x16x32_bf16(ah[mt], wl[nt][ks], acc[mt][nt], 0, 0, 0);
                acc[mt][nt] = __builtin_amdgcn_mfma_f32_16x16x32_bf16(al[mt], wh[nt][ks], acc[mt][nt], 0, 0, 0);
            }
    }
}

// stage 64xK fp32 tile -> hi/lo LDS planes (8 float4/thread)
__device__ __forceinline__ void stage_f32(const float* __restrict__ A, int i0, int t,
                                          unsigned short* Ph, unsigned short* Pl) {
#pragma unroll
    for (int p = 0; p < 8; p++) {
        int c = t + p * 256;
        int row = c >> 5, cc = (c & 31) * 4;
        int gi = min(i0 + row, NN - 1);
        float4 v = *(const float4*)&A[(size_t)gi * KD + cc];
        ushort4v h, l;
        h.x = f2bf(v.x); l.x = f2bf(v.x - bfh2f(h.x));
        h.y = f2bf(v.y); l.y = f2bf(v.y - bfh2f(h.y));
        h.z = f2bf(v.z); l.z = f2bf(v.z - bfh2f(h.z));
        h.w = f2bf(v.w); l.w = f2bf(v.w - bfh2f(h.w));
        *(ushort4v*)&Ph[row * LDK + cc] = h;
        *(ushort4v*)&Pl[row * LDK + cc] = l;
    }
}

// stage 64xK packed tile -> hi/lo LDS planes
__device__ __forceinline__ void stage_packed(const unsigned* __restrict__ A, int i0, int t,
                                             unsigned short* Ph, unsigned short* Pl) {
#pragma unroll
    for (int p = 0; p < 8; p++) {
        int c = t + p * 256;
        int row = c >> 5, cc = (c & 31) * 4;
        int gi = min(i0 + row, NN - 1);
        uint4 u = *(const uint4*)&A[(size_t)gi * KD + cc];
        ushort4v h, l;
        h.x = (unsigned short)(u.x >> 16); l.x = (unsigned short)(u.x & 0xFFFF);
        h.y = (unsigned short)(u.y >> 16); l.y = (unsigned short)(u.y & 0xFFFF);
        h.z = (unsigned short)(u.z >> 16); l.z = (unsigned short)(u.z & 0xFFFF);
        h.w = (unsigned short)(u.w >> 16); l.w = (unsigned short)(u.w & 0xFFFF);
        *(ushort4v*)&Ph[row * LDK + cc] = h;
        *(ushort4v*)&Pl[row * LDK + cc] = l;
    }
}

// ------------------------------------------------- fused sage+res+stats ----
// B0 = mean@Wl^T + x@Wr^T + bs (sage); B1 = x@We^T + br (res);
// bnacc[col] += colsum(B0), bnacc[128+col] += colsumsq(B0).
template <bool A2PACKED>
__global__ __launch_bounds__(256, 2) void fused_sage_kernel(
    const float* __restrict__ A1f,
    const float* __restrict__ A2f, const unsigned* __restrict__ A2p,
    const unsigned short* __restrict__ Wlh, const unsigned short* __restrict__ Wll,
    const unsigned short* __restrict__ Wrh, const unsigned short* __restrict__ Wrl,
    const unsigned short* __restrict__ Weh, const unsigned short* __restrict__ Wel,
    const float* __restrict__ bs, const float* __restrict__ br,
    float* __restrict__ B0, float* __restrict__ B1, float* __restrict__ bnacc) {
    __shared__ __align__(16) unsigned short Ph[64 * LDK];
    __shared__ __align__(16) unsigned short Pl[64 * LDK];
    const int t = threadIdx.x;
    const int i0 = blockIdx.x * 64;
    const int w = t >> 6, lane = t & 63, quad = lane >> 4, mm = lane & 15;
    const int colb = w * 32;

    f32x4 accs[4][2] = {};
    // phase 1: mean @ Wl
    stage_f32(A1f, i0, t, Ph, Pl);
    __syncthreads();
    product_from_lds<2>(Ph, Pl, Wlh, Wll, colb, quad, mm, accs);
    __syncthreads();                       // A1 reads done
    // phase 2: x @ Wr (sage) and x @ We (res)
    if (A2PACKED) stage_packed(A2p, i0, t, Ph, Pl);
    else          stage_f32(A2f, i0, t, Ph, Pl);
    __syncthreads();
    product_from_lds<2>(Ph, Pl, Wrh, Wrl, colb, quad, mm, accs);
    f32x4 accr[4][2] = {};
    product_from_lds<2>(Ph, Pl, Weh, Wel, colb, quad, mm, accr);

    // epilogue: sage -> B0 (+stats), res -> B1
    float s[2] = {0, 0}, q[2] = {0, 0};
#pragma unroll
    for (int nt = 0; nt < 2; nt++) {
        int col = colb + nt * 16 + mm;
        float bvs = bs[col], bvr = br[col];
#pragma unroll
        for (int mt = 0; mt < 4; mt++)
#pragma unroll
            for (int r = 0; r < 4; r++) {
                int row = i0 + mt * 16 + quad * 4 + r;
                if (row < NN) {
                    float vs = accs[mt][nt][r] + bvs;
                    float vr = accr[mt][nt][r] + bvr;
                    B0[(size_t)row * KD + col] = vs;
                    B1[(size_t)row * KD + col] = vr;
                    s[nt] += vs;
                    q[nt] += vs * vs;
                }
            }
    }
#pragma unroll
    for (int nt = 0; nt < 2; nt++) {
        float ss = s[nt], qq = q[nt];
        ss += __shfl_xor(ss, 16); ss += __shfl_xor(ss, 32);
        qq += __shfl_xor(qq, 16); qq += __shfl_xor(qq, 32);
        if (quad == 0) {
            int col = colb + nt * 16 + mm;
            atomicAdd(&bnacc[col], ss);
            atomicAdd(&bnacc[128 + col], qq);
        }
    }
}

// ----------------------------------------- fused block3: sage3+ff1+ff2+clf ----
__global__ __launch_bounds__(256, 2) void fused_block3_kernel(
    const float* __restrict__ Mf, const unsigned* __restrict__ Hp,
    const unsigned short* __restrict__ Wlh, const unsigned short* __restrict__ Wll,
    const unsigned short* __restrict__ Wrh, const unsigned short* __restrict__ Wrl,
    const unsigned short* __restrict__ F1h, const unsigned short* __restrict__ F1l,
    const unsigned short* __restrict__ F2h, const unsigned short* __restrict__ F2l,
    const unsigned short* __restrict__ Ch,  const unsigned short* __restrict__ Cl,
    const float* __restrict__ s3_b, const float* __restrict__ ff1_b,
    const float* __restrict__ ff2_b, const float* __restrict__ clf_b,
    float* __restrict__ out) {
    __shared__ __align__(16) unsigned short Ph[64 * LDK];
    __shared__ __align__(16) unsigned short Pl[64 * LDK];
    const int t = threadIdx.x;
    const int i0 = blockIdx.x * 64;
    const int w = t >> 6, lane = t & 63, quad = lane >> 4, mm = lane & 15;
    const int colb = w * 32;

    // write acc (+bias, opt relu) as hi/lo planes back into LDS
    auto write_lds = [&](f32x4 (&acc)[4][2], const float* bias, bool relu) {
#pragma unroll
        for (int nt = 0; nt < 2; nt++) {
            int col = colb + nt * 16 + mm;
            float bv = bias[col];
#pragma unroll
            for (int mt = 0; mt < 4; mt++)
#pragma unroll
                for (int r = 0; r < 4; r++) {
                    int row = mt * 16 + quad * 4 + r;
                    float v = acc[mt][nt][r] + bv;
                    if (relu) v = fmaxf(v, 0.0f);
                    unsigned short h = f2bf(v);
                    Ph[row * LDK + col] = h;
                    Pl[row * LDK + col] = f2bf(v - bfh2f(h));
                }
        }
    };

    // ---- sage3: mean @ Wl + h @ Wr + b ----
    f32x4 acc[4][2] = {};
    stage_f32(Mf, i0, t, Ph, Pl);
    __syncthreads();
    product_from_lds<2>(Ph, Pl, Wlh, Wll, colb, quad, mm, acc);
    __syncthreads();
    stage_packed(Hp, i0, t, Ph, Pl);
    __syncthreads();
    product_from_lds<2>(Ph, Pl, Wrh, Wrl, colb, quad, mm, acc);
    __syncthreads();                       // all reads done before overwrite
    write_lds(acc, s3_b, false);
    __syncthreads();

    // ---- ff1 (+relu) ----
    f32x4 acc2[4][2] = {};
    product_from_lds<2>(Ph, Pl, F1h, F1l, colb, quad, mm, acc2);
    __syncthreads();
    write_lds(acc2, ff1_b, true);
    __syncthreads();

    // ---- ff2 ----
    f32x4 acc3[4][2] = {};
    product_from_lds<2>(Ph, Pl, F2h, F2l, colb, quad, mm, acc3);
    __syncthreads();
    write_lds(acc3, ff2_b, false);
    __syncthreads();

    // ---- clf (NOUT=64): waves cover cols w*16..w*16+15 ----
    f32x4 acc4[4][1] = {};
    product_from_lds<1>(Ph, Pl, Ch, Cl, w * 16, quad, mm, acc4);
    {
        int col = w * 16 + mm;
        float bv = clf_b[col];
#pragma unroll
        for (int mt = 0; mt < 4; mt++)
#pragma unroll
            for (int r = 0; r < 4; r++) {
                int row = i0 + mt * 16 + quad * 4 + r;
                if (row < NN) out[(size_t)row * 64 + col] = acc4[mt][0][r] + bv;
            }
    }
}

// ------------------------------------------------------------------ BN ----
__global__ void bnfinal_kernel(const float* __restrict__ acc, const float* __restrict__ g,
                               const float* __restrict__ b, float* __restrict__ scsh) {
    int c = threadIdx.x;
    float mean = acc[c] * (1.0f / NN);
    float var = acc[128 + c] * (1.0f / NN) - mean * mean;
    float sc = g[c] * rsqrtf(var + EPSF);
    scsh[c] = sc;
    scsh[128 + c] = b[c] - mean * sc;
}

// h = relu(Y*scale+shift)+R -> packed hi/lo (gather + GEMM source)
__global__ void bnrelures_kernel(const float* __restrict__ Y, const float* __restrict__ R,
                                 const float* __restrict__ scsh, unsigned* __restrict__ Op) {
    int idx = blockIdx.x * blockDim.x + threadIdx.x;
    const int total = NN * KD / 4;
    if (idx >= total) return;
    int cg = idx & 31;
    float4 y = ((const float4*)Y)[idx];
    float4 r = ((const float4*)R)[idx];
    float4 sc = ((const float4*)scsh)[cg];
    float4 sh = ((const float4*)scsh)[32 + cg];
    uint4 o;
    o.x = packf(fmaxf(y.x * sc.x + sh.x, 0.0f) + r.x);
    o.y = packf(fmaxf(y.y * sc.y + sh.y, 0.0f) + r.y);
    o.z = packf(fmaxf(y.z * sc.z + sh.z, 0.0f) + r.z);
    o.w = packf(fmaxf(y.w * sc.w + sh.w, 0.0f) + r.w);
    ((uint4*)Op)[idx] = o;
}

// --------------------------------------------------------------- launch ----
extern "C" void kernel_launch(void* const* d_in, const int* in_sizes, int n_in,
                              void* d_out, int out_size, void* d_ws, size_t ws_size,
                              hipStream_t stream) {
    const float* x      = (const float*)d_in[0];
    const int*   ei     = (const int*)d_in[1];
    const int*   e_src  = ei;
    const int*   e_dst  = ei + NE;
    const float* s1_b   = (const float*)d_in[4];
    const float* s2_b   = (const float*)d_in[7];
    const float* s3_b   = (const float*)d_in[10];
    const float* bn1_g  = (const float*)d_in[11];
    const float* bn1_b  = (const float*)d_in[12];
    const float* bn2_g  = (const float*)d_in[13];
    const float* bn2_b  = (const float*)d_in[14];
    const float* res1_b = (const float*)d_in[16];
    const float* res2_b = (const float*)d_in[18];
    const float* ff1_b  = (const float*)d_in[20];
    const float* ff2_b  = (const float*)d_in[22];
    const float* clf_b  = (const float*)d_in[24];
    float* out = (float*)d_out;

    // workspace carve-up (256B aligned); peak ~215 MB
    char* w = (char*)d_ws;
    auto alloc = [&](size_t bytes) { char* p = w; w += (bytes + 255) & ~(size_t)255; return p; };
    float*    B0   = (float*)alloc((size_t)NN * KD * 4);     // sage out fp32
    float*    B1   = (float*)alloc((size_t)NN * KD * 4);     // res out fp32
    float*    Mf   = (float*)alloc((size_t)NN * KD * 4);     // mean fp32
    unsigned* Hp   = (unsigned*)alloc((size_t)NN * KD * 4);  // packed h
    int*   row_start = (int*)alloc((NN + 1) * 4);
    int*   cursor    = (int*)alloc(NN * 4);
    int*   sorted    = (int*)alloc((size_t)NE * 4);
    float* deg_inv   = (float*)alloc(NN * 4);
    float* bnacc     = (float*)alloc(512 * 4);
    float* bnscsh    = (float*)alloc(512 * 4);
    int*   bsum      = (int*)alloc(SCAN_G * 4);
    unsigned short* Wpl = (unsigned short*)alloc((size_t)22 * WPLANE * 2);

    auto WH = [&](int j) { return Wpl + (size_t)j * WPLANE; };
    auto WL = [&](int j) { return Wpl + (size_t)(11 + j) * WPLANE; };

    const int GN = (NN + 255) / 256;
    const int GG = (NN + 63) / 64;                 // 1563 fused-GEMM blocks
    const int GA = (NN + 7) / 8;
    const int GV = (NN * KD / 4 + 255) / 256;
    const int GR = RNG * BPR;

    // ---- CSR build (range-partitioned) ----
    zero_init_kernel<<<GN, 256, 0, stream>>>(cursor, bnacc);
    hist_ranged_kernel<<<GR, 256, 0, stream>>>(e_dst, cursor);
    bsum_kernel<<<SCAN_G, 256, 0, stream>>>(cursor, bsum);
    scan_bsum_kernel<<<1, 512, 0, stream>>>(bsum);
    scan_local_kernel<<<SCAN_G, 256, 0, stream>>>(cursor, bsum, row_start, deg_inv);
    scatter_ranged_kernel<<<GR, 256, 0, stream>>>(e_src, e_dst, cursor, sorted);

    // ---- weights ----
    wconv_kernel<<<(43008 + 255) / 256, 256, 0, stream>>>(
        (const float*)d_in[15], (const float*)d_in[2], (const float*)d_in[3],   // res1_w(0), s1_wl(1), s1_wr(2)
        (const float*)d_in[17], (const float*)d_in[5], (const float*)d_in[6],   // res2_w(3), s2_wl(4), s2_wr(5)
        (const float*)d_in[8], (const float*)d_in[9],                            // s3_wl(6), s3_wr(7)
        (const float*)d_in[19], (const float*)d_in[21], (const float*)d_in[23], // ff1(8), ff2(9), clf(10)
        Wpl);

    // ---- block 1 ----
    aggregate_kernel<false><<<GA, 256, 0, stream>>>(x, nullptr, row_start, sorted, deg_inv, Mf);
    fused_sage_kernel<false><<<GG, 256, 0, stream>>>(
        Mf, x, nullptr, WH(1), WL(1), WH(2), WL(2), WH(0), WL(0), s1_b, res1_b, B0, B1, bnacc);
    bnfinal_kernel<<<1, 128, 0, stream>>>(bnacc, bn1_g, bn1_b, bnscsh);
    bnrelures_kernel<<<GV, 256, 0, stream>>>(B0, B1, bnscsh, Hp);                // h1 -> Hp

    // ---- block 2 ----
    aggregate_kernel<true><<<GA, 256, 0, stream>>>(nullptr, Hp, row_start, sorted, deg_inv, Mf);
    fused_sage_kernel<true><<<GG, 256, 0, stream>>>(
        Mf, nullptr, Hp, WH(4), WL(4), WH(5), WL(5), WH(3), WL(3), s2_b, res2_b, B0, B1, bnacc + 256);
    bnfinal_kernel<<<1, 128, 0, stream>>>(bnacc + 256, bn2_g, bn2_b, bnscsh + 256);
    bnrelures_kernel<<<GV, 256, 0, stream>>>(B0, B1, bnscsh + 256, Hp);          // h2 -> Hp

    // ---- block 3 + head (fully fused) ----
    aggregate_kernel<true><<<GA, 256, 0, stream>>>(nullptr, Hp, row_start, sorted, deg_inv, Mf);
    fused_block3_kernel<<<GG, 256, 0, stream>>>(
        Mf, Hp, WH(6), WL(6), WH(7), WL(7), WH(8), WL(8), WH(9), WL(9), WH(10), WL(10),
        s3_b, ff1_b, ff2_b, clf_b, out);
}